// Round 9
// baseline (59.665 us; speedup 1.0000x reference)
//
#include <hip/hip_runtime.h>

#define B_DIM 256
#define L_DIM 32768
#define CHUNK 4096
#define HALO  100
#define NREAL (CHUNK + 2*HALO)   // 4296 (indices >= NREAL never read in phase 5)
#define T     512
#define EPT   9
#define NPAD  (T*EPT)            // 4608
#define NG    (NPAD/4)           // 1152 float4 groups
#define NWAVE (T/64)             // 8

typedef float fx4 __attribute__((ext_vector_type(4)));

__global__ __launch_bounds__(T) void pool_feat_kernel(const float* __restrict__ x,
                                                      float* __restrict__ out) {
    const int row    = blockIdx.y;
    const int chunk0 = blockIdx.x * CHUNK;
    const int tid    = threadIdx.x;

    // sA stages raw x first, then is overwritten (per-thread-own-segment,
    // with a barrier before any cross-thread read) by the a-cumsum.
    __shared__ __align__(16) float sA[NPAD];
    __shared__ __align__(16) float sB[NPAD];
    __shared__ float waveA[NWAVE];
    __shared__ float waveB[NWAVE];

    const float* xr = x + (size_t)row * L_DIM;

    // Phase 1: coalesced float4 staging of raw x (zero-fill outside the row).
    // Pad region [NREAL, NPAD) may hold garbage/next-cols: provably unused.
    for (int g = tid; g < NG; g += T) {
        const int c = chunk0 - HALO + 4 * g;   // 4-aligned (HALO%4==0)
        fx4 v;
        if (c >= 0 && c + 3 < L_DIM) {
            v = *reinterpret_cast<const fx4*>(xr + c);
        } else {
            v.x = (c + 0 >= 0 && c + 0 < L_DIM) ? xr[c + 0] : 0.0f;
            v.y = (c + 1 >= 0 && c + 1 < L_DIM) ? xr[c + 1] : 0.0f;
            v.z = (c + 2 >= 0 && c + 2 < L_DIM) ? xr[c + 2] : 0.0f;
            v.w = (c + 3 >= 0 && c + 3 < L_DIM) ? xr[c + 3] : 0.0f;
        }
        *reinterpret_cast<fx4*>(&sA[4 * g]) = v;
    }
    __syncthreads();

    // Phase 2 (pass 1): per-thread segment TOTALS only — no register arrays.
    const int s0 = tid * EPT;
    float runA = 0.0f, runB = 0.0f;
    #pragma unroll
    for (int j = 0; j < EPT; ++j) {
        const float v = sA[s0 + j];
        runA += __logf(fmaxf(1.0f, 1.0f + v));
        runB += __logf(fmaxf(1.0f, 1.0f - v));
    }

    // Phase 3: block scan of segment totals (wave shuffle + wave totals)
    float vA = runA, vB = runB;
    const int lane = tid & 63;
    const int wid  = tid >> 6;
    #pragma unroll
    for (int d = 1; d < 64; d <<= 1) {
        float uA = __shfl_up(vA, d);
        float uB = __shfl_up(vB, d);
        if (lane >= d) { vA += uA; vB += uB; }
    }
    if (lane == 63) { waveA[wid] = vA; waveB[wid] = vB; }
    __syncthreads();
    float offA = vA - runA;   // exclusive prefix within wave
    float offB = vB - runB;
    #pragma unroll
    for (int w = 0; w < NWAVE - 1; ++w) {
        if (w < wid) { offA += waveA[w]; offB += waveB[w]; }
    }

    // Phase 4 (pass 2): recompute transform, write final cumsum to LDS.
    // Reads own segment of sA before overwriting each element — no hazard.
    float accA = offA, accB = offB;
    #pragma unroll
    for (int j = 0; j < EPT; ++j) {
        const float v = sA[s0 + j];
        accA += __logf(fmaxf(1.0f, 1.0f + v));
        accB += __logf(fmaxf(1.0f, 1.0f - v));
        sA[s0 + j] = accA;
        sB[s0 + j] = accB;
    }
    __syncthreads();

    // Phase 5: 8 outputs/thread; all LDS reads are aligned ds_read_b128.
    //   cs[i+u]:    V0,V1   (i0+0..7)
    //   cs[i+98+u]: W0,W1,W2 (i0+96..107)   cs[i+101+u]: W1,W2,W3 (i0+100..111)
    //   cs[i+199+u]: X0,X1,X2 (i0+196..207)
    const float inv3   = 1.0f / 3.0f;
    const float inv199 = 1.0f / 199.0f;
    const int i0 = 8 * tid;                       // 0..4088, covers CHUNK
    float* ob = out + (size_t)row * 4u * L_DIM + chunk0 + i0;
    #pragma unroll
    for (int arr = 0; arr < 2; ++arr) {
        const float* s = arr ? sB : sA;
        const fx4 V0 = *reinterpret_cast<const fx4*>(s + i0);
        const fx4 V1 = *reinterpret_cast<const fx4*>(s + i0 + 4);
        const fx4 W0 = *reinterpret_cast<const fx4*>(s + i0 + 96);
        const fx4 W1 = *reinterpret_cast<const fx4*>(s + i0 + 100);
        const fx4 W2 = *reinterpret_cast<const fx4*>(s + i0 + 104);
        const fx4 W3 = *reinterpret_cast<const fx4*>(s + i0 + 108);
        const fx4 X0 = *reinterpret_cast<const fx4*>(s + i0 + 196);
        const fx4 X1 = *reinterpret_cast<const fx4*>(s + i0 + 200);
        const fx4 X2 = *reinterpret_cast<const fx4*>(s + i0 + 204);
        const float csI[8]   = {V0.x,V0.y,V0.z,V0.w, V1.x,V1.y,V1.z,V1.w};
        const float cs98[8]  = {W0.z,W0.w, W1.x,W1.y,W1.z,W1.w, W2.x,W2.y};
        const float cs101[8] = {W1.y,W1.z,W1.w, W2.x,W2.y,W2.z,W2.w, W3.x};
        const float cs199[8] = {X0.w, X1.x,X1.y,X1.z,X1.w, X2.x,X2.y,X2.z};
        float ps[8], pd[8];
        #pragma unroll
        for (int u = 0; u < 8; ++u) {
            const float p0 = (cs101[u] - cs98[u]) * inv3;
            const float p5 = (cs199[u] - csI[u]) * inv199;
            ps[u] = p0;
            pd[u] = p0 - p5;
        }
        float* od = ob + (size_t)(arr ? 2 : 0) * L_DIM;   // diff plane
        float* os = ob + (size_t)(arr ? 3 : 1) * L_DIM;   // plain k=3 plane
        fx4 t;
        t.x=pd[0]; t.y=pd[1]; t.z=pd[2]; t.w=pd[3];
        __builtin_nontemporal_store(t, reinterpret_cast<fx4*>(od));
        t.x=pd[4]; t.y=pd[5]; t.z=pd[6]; t.w=pd[7];
        __builtin_nontemporal_store(t, reinterpret_cast<fx4*>(od + 4));
        t.x=ps[0]; t.y=ps[1]; t.z=ps[2]; t.w=ps[3];
        __builtin_nontemporal_store(t, reinterpret_cast<fx4*>(os));
        t.x=ps[4]; t.y=ps[5]; t.z=ps[6]; t.w=ps[7];
        __builtin_nontemporal_store(t, reinterpret_cast<fx4*>(os + 4));
    }
}

extern "C" void kernel_launch(void* const* d_in, const int* in_sizes, int n_in,
                              void* d_out, int out_size, void* d_ws, size_t ws_size,
                              hipStream_t stream) {
    const float* x = (const float*)d_in[0];
    float* out = (float*)d_out;
    dim3 grid(L_DIM / CHUNK, B_DIM);
    pool_feat_kernel<<<grid, dim3(T), 0, stream>>>(x, out);
}

// Round 10
// 33.464 us; speedup vs baseline: 1.7830x; 1.7830x over previous
//
#include <hip/hip_runtime.h>

#define B_DIM 256
#define L_DIM 32768
#define CHUNK 2048
#define HALO  100
#define NTOT  (CHUNK + 2*HALO)   // 2248
#define NG    (NTOT/4)           // 562 float4 groups
#define T     256
#define EPT   9                  // ceil(NTOT / T)

typedef float fx4 __attribute__((ext_vector_type(4)));

__global__ __launch_bounds__(T) void pool_feat_kernel(const float* __restrict__ x,
                                                      float* __restrict__ out) {
    const int row    = blockIdx.y;
    const int chunk0 = blockIdx.x * CHUNK;
    const int tid    = threadIdx.x;

    // sA stages raw x first, then is overwritten (per-thread-own-segment,
    // with a barrier before any cross-thread read) by the a-cumsum.
    __shared__ __align__(16) float sA[NTOT];
    __shared__ __align__(16) float sB[NTOT];
    __shared__ float waveA[4];
    __shared__ float waveB[4];

    const float* xr = x + (size_t)row * L_DIM;

    // Phase 1: coalesced float4 staging of raw x (zero-fill outside the row)
    for (int g = tid; g < NG; g += T) {
        const int c = chunk0 - HALO + 4 * g;   // 4-aligned (HALO%4==0)
        fx4 v;
        if (c >= 0 && c + 3 < L_DIM) {
            v = *reinterpret_cast<const fx4*>(xr + c);
        } else {
            v.x = (c + 0 >= 0 && c + 0 < L_DIM) ? xr[c + 0] : 0.0f;
            v.y = (c + 1 >= 0 && c + 1 < L_DIM) ? xr[c + 1] : 0.0f;
            v.z = (c + 2 >= 0 && c + 2 < L_DIM) ? xr[c + 2] : 0.0f;
            v.w = (c + 3 >= 0 && c + 3 < L_DIM) ? xr[c + 3] : 0.0f;
        }
        *reinterpret_cast<fx4*>(&sA[4 * g]) = v;
    }
    __syncthreads();

    // Phase 2 (pass 1): per-thread segment TOTALS only — no register arrays,
    // so nothing bulky stays live across the scan.
    const int s0 = tid * EPT;
    const int s1 = min(NTOT, s0 + EPT);
    float runA = 0.0f, runB = 0.0f;
    for (int j = s0; j < s1; ++j) {
        const float v = sA[j];
        runA += __logf(fmaxf(1.0f, 1.0f + v));
        runB += __logf(fmaxf(1.0f, 1.0f - v));
    }

    // Phase 3: block scan of segment totals (wave shuffle + wave totals)
    float vA = runA, vB = runB;
    const int lane = tid & 63;
    const int wid  = tid >> 6;
    #pragma unroll
    for (int d = 1; d < 64; d <<= 1) {
        float uA = __shfl_up(vA, d);
        float uB = __shfl_up(vB, d);
        if (lane >= d) { vA += uA; vB += uB; }
    }
    if (lane == 63) { waveA[wid] = vA; waveB[wid] = vB; }
    __syncthreads();
    float offA = vA - runA;   // exclusive prefix within wave
    float offB = vB - runB;
    #pragma unroll
    for (int w = 0; w < 3; ++w) {
        if (w < wid) { offA += waveA[w]; offB += waveB[w]; }
    }

    // Phase 4 (pass 2): recompute transform, write final cumsum to LDS.
    // Reads own segment of sA before overwriting each element — no hazard.
    float accA = offA, accB = offB;
    for (int j = s0; j < s1; ++j) {
        const float v = sA[j];
        accA += __logf(fmaxf(1.0f, 1.0f + v));
        accB += __logf(fmaxf(1.0f, 1.0f - v));
        sA[j] = accA;
        sB[j] = accB;
    }
    __syncthreads();

    // Phase 5: windows via aligned ds_read_b128 only (conflict-free pattern),
    // shifted windows assembled by register selects from adjacent float4s.
    //   cs[i]     -> L0[u]                  (L0 = cs[i0+0..3])
    //   cs[i+98]  -> {L1.z,L1.w,L2.x,L2.y}  (L1 = cs[i0+96..99], L2 = cs[i0+100..103])
    //   cs[i+101] -> {L2.y,L2.z,L2.w,L3.x}  (L3 = cs[i0+104..107])
    //   cs[i+199] -> {L4.w,L5.x,L5.y,L5.z}  (L4 = cs[i0+196..199], L5 = cs[i0+200..203])
    const float inv3   = 1.0f / 3.0f;
    const float inv199 = 1.0f / 199.0f;
    float* ob = out + (size_t)row * 4u * L_DIM + chunk0;
    #pragma unroll
    for (int it = 0; it < CHUNK / (4 * T); ++it) {   // 2 iterations
        const int i0 = 4 * (tid + it * T);
        fx4 r0, r1, r2, r3;
        #pragma unroll
        for (int arr = 0; arr < 2; ++arr) {
            const float* s = arr ? sB : sA;
            const fx4 L0 = *reinterpret_cast<const fx4*>(s + i0);
            const fx4 L1 = *reinterpret_cast<const fx4*>(s + i0 + 96);
            const fx4 L2 = *reinterpret_cast<const fx4*>(s + i0 + 100);
            const fx4 L3 = *reinterpret_cast<const fx4*>(s + i0 + 104);
            const fx4 L4 = *reinterpret_cast<const fx4*>(s + i0 + 196);
            const fx4 L5 = *reinterpret_cast<const fx4*>(s + i0 + 200);
            const float csI[4]   = {L0.x, L0.y, L0.z, L0.w};
            const float cs98[4]  = {L1.z, L1.w, L2.x, L2.y};
            const float cs101[4] = {L2.y, L2.z, L2.w, L3.x};
            const float cs199[4] = {L4.w, L5.x, L5.y, L5.z};
            fx4& rs = arr ? r3 : r1;   // plain k=3 pool
            fx4& rd = arr ? r2 : r0;   // k=3 - k=199
            #pragma unroll
            for (int u = 0; u < 4; ++u) {
                const float p0 = (cs101[u] - cs98[u]) * inv3;
                const float p5 = (cs199[u] - csI[u]) * inv199;
                rs[u] = p0;
                rd[u] = p0 - p5;
            }
        }
        __builtin_nontemporal_store(r0, reinterpret_cast<fx4*>(ob + 0 * (size_t)L_DIM + i0));
        __builtin_nontemporal_store(r1, reinterpret_cast<fx4*>(ob + 1 * (size_t)L_DIM + i0));
        __builtin_nontemporal_store(r2, reinterpret_cast<fx4*>(ob + 2 * (size_t)L_DIM + i0));
        __builtin_nontemporal_store(r3, reinterpret_cast<fx4*>(ob + 3 * (size_t)L_DIM + i0));
    }
}

extern "C" void kernel_launch(void* const* d_in, const int* in_sizes, int n_in,
                              void* d_out, int out_size, void* d_ws, size_t ws_size,
                              hipStream_t stream) {
    const float* x = (const float*)d_in[0];
    float* out = (float*)d_out;
    dim3 grid(L_DIM / CHUNK, B_DIM);
    pool_feat_kernel<<<grid, dim3(T), 0, stream>>>(x, out);
}

// Round 11
// 32.646 us; speedup vs baseline: 1.8276x; 1.0251x over previous
//
#include <hip/hip_runtime.h>

#define B_DIM 256
#define L_DIM 32768
#define CHUNK 2048
#define HALO  100
#define NTOT  (CHUNK + 2*HALO)   // 2248
#define NG    (NTOT/4)           // 562 float4 groups
#define T     256
#define EPT   9                  // ceil(NTOT / T)

typedef float fx4 __attribute__((ext_vector_type(4)));

__global__ __launch_bounds__(T) void pool_feat_kernel(const float* __restrict__ x,
                                                      float* __restrict__ out) {
    const int row    = blockIdx.y;
    const int chunk0 = blockIdx.x * CHUNK;
    const int tid    = threadIdx.x;

    // sA stages raw x first, then is overwritten (per-thread-own-segment,
    // with a barrier before any cross-thread read) by the a-cumsum.
    __shared__ __align__(16) float sA[NTOT];
    __shared__ __align__(16) float sB[NTOT];
    __shared__ float waveA[4];
    __shared__ float waveB[4];

    const float* xr = x + (size_t)row * L_DIM;

    // Phase 1: coalesced float4 staging of raw x (zero-fill outside the row)
    for (int g = tid; g < NG; g += T) {
        const int c = chunk0 - HALO + 4 * g;   // 4-aligned (HALO%4==0)
        fx4 v;
        if (c >= 0 && c + 3 < L_DIM) {
            v = *reinterpret_cast<const fx4*>(xr + c);
        } else {
            v.x = (c + 0 >= 0 && c + 0 < L_DIM) ? xr[c + 0] : 0.0f;
            v.y = (c + 1 >= 0 && c + 1 < L_DIM) ? xr[c + 1] : 0.0f;
            v.z = (c + 2 >= 0 && c + 2 < L_DIM) ? xr[c + 2] : 0.0f;
            v.w = (c + 3 >= 0 && c + 3 < L_DIM) ? xr[c + 3] : 0.0f;
        }
        *reinterpret_cast<fx4*>(&sA[4 * g]) = v;
    }
    __syncthreads();

    // Phase 2: per-thread transform + inclusive cumsum in registers.
    // KEY: log(max(1,1+x)) and log(max(1,1-x)) are never both nonzero:
    //   t = log(1+|x|);  a-term = (x>0) ? t : 0;  b-term = (x<0) ? t : 0.
    // One transcendental per element instead of two.
    const int s0 = tid * EPT;
    const int s1 = min(NTOT, s0 + EPT);
    float ra[EPT], rb[EPT];
    float runA = 0.0f, runB = 0.0f;
    #pragma unroll
    for (int j = 0; j < EPT; ++j) {
        const int idx = s0 + j;
        const float v = (idx < s1) ? sA[idx] : 0.0f;
        const float t = __logf(1.0f + fabsf(v));
        runA += (v > 0.0f) ? t : 0.0f;
        runB += (v < 0.0f) ? t : 0.0f;
        ra[j] = runA; rb[j] = runB;
    }

    // Phase 3: block scan of segment totals (wave shuffle + wave totals)
    float vA = runA, vB = runB;
    const int lane = tid & 63;
    const int wid  = tid >> 6;
    #pragma unroll
    for (int d = 1; d < 64; d <<= 1) {
        float uA = __shfl_up(vA, d);
        float uB = __shfl_up(vB, d);
        if (lane >= d) { vA += uA; vB += uB; }
    }
    if (lane == 63) { waveA[wid] = vA; waveB[wid] = vB; }
    __syncthreads();
    float offA = vA - runA;   // exclusive prefix within wave
    float offB = vB - runB;
    #pragma unroll
    for (int w = 0; w < 3; ++w) {
        if (w < wid) { offA += waveA[w]; offB += waveB[w]; }
    }

    // Phase 4: single write pass of the final cumsum into LDS
    #pragma unroll
    for (int j = 0; j < EPT; ++j) {
        const int idx = s0 + j;
        if (idx < NTOT) { sA[idx] = ra[j] + offA; sB[idx] = rb[j] + offB; }
    }
    __syncthreads();

    // Phase 5: windows via aligned ds_read_b128 only (conflict-free pattern),
    // shifted windows assembled by register selects from adjacent float4s.
    //   cs[i]     -> L0[u]                  (L0 = cs[i0+0..3])
    //   cs[i+98]  -> {L1.z,L1.w,L2.x,L2.y}  (L1 = cs[i0+96..99], L2 = cs[i0+100..103])
    //   cs[i+101] -> {L2.y,L2.z,L2.w,L3.x}  (L3 = cs[i0+104..107])
    //   cs[i+199] -> {L4.w,L5.x,L5.y,L5.z}  (L4 = cs[i0+196..199], L5 = cs[i0+200..203])
    const float inv3   = 1.0f / 3.0f;
    const float inv199 = 1.0f / 199.0f;
    float* ob = out + (size_t)row * 4u * L_DIM + chunk0;
    #pragma unroll
    for (int it = 0; it < CHUNK / (4 * T); ++it) {   // 2 iterations
        const int i0 = 4 * (tid + it * T);
        fx4 r0, r1, r2, r3;
        #pragma unroll
        for (int arr = 0; arr < 2; ++arr) {
            const float* s = arr ? sB : sA;
            const fx4 L0 = *reinterpret_cast<const fx4*>(s + i0);
            const fx4 L1 = *reinterpret_cast<const fx4*>(s + i0 + 96);
            const fx4 L2 = *reinterpret_cast<const fx4*>(s + i0 + 100);
            const fx4 L3 = *reinterpret_cast<const fx4*>(s + i0 + 104);
            const fx4 L4 = *reinterpret_cast<const fx4*>(s + i0 + 196);
            const fx4 L5 = *reinterpret_cast<const fx4*>(s + i0 + 200);
            const float csI[4]   = {L0.x, L0.y, L0.z, L0.w};
            const float cs98[4]  = {L1.z, L1.w, L2.x, L2.y};
            const float cs101[4] = {L2.y, L2.z, L2.w, L3.x};
            const float cs199[4] = {L4.w, L5.x, L5.y, L5.z};
            fx4& rs = arr ? r3 : r1;   // plain k=3 pool
            fx4& rd = arr ? r2 : r0;   // k=3 - k=199
            #pragma unroll
            for (int u = 0; u < 4; ++u) {
                const float p0 = (cs101[u] - cs98[u]) * inv3;
                const float p5 = (cs199[u] - csI[u]) * inv199;
                rs[u] = p0;
                rd[u] = p0 - p5;
            }
        }
        __builtin_nontemporal_store(r0, reinterpret_cast<fx4*>(ob + 0 * (size_t)L_DIM + i0));
        __builtin_nontemporal_store(r1, reinterpret_cast<fx4*>(ob + 1 * (size_t)L_DIM + i0));
        __builtin_nontemporal_store(r2, reinterpret_cast<fx4*>(ob + 2 * (size_t)L_DIM + i0));
        __builtin_nontemporal_store(r3, reinterpret_cast<fx4*>(ob + 3 * (size_t)L_DIM + i0));
    }
}

extern "C" void kernel_launch(void* const* d_in, const int* in_sizes, int n_in,
                              void* d_out, int out_size, void* d_ws, size_t ws_size,
                              hipStream_t stream) {
    const float* x = (const float*)d_in[0];
    float* out = (float*)d_out;
    dim3 grid(L_DIM / CHUNK, B_DIM);
    pool_feat_kernel<<<grid, dim3(T), 0, stream>>>(x, out);
}

// Round 12
// 32.606 us; speedup vs baseline: 1.8299x; 1.0012x over previous
//
#include <hip/hip_runtime.h>

#define B_DIM 256
#define L_DIM 32768
#define CHUNK 2048
#define HALO  100
#define NTOT  (CHUNK + 2*HALO)   // 2248
#define NG    (NTOT/4)           // 562 float4 groups
#define T     256
#define EPT   9                  // ceil(NTOT / T)

typedef float fx4 __attribute__((ext_vector_type(4)));

__global__ __launch_bounds__(T) void pool_feat_kernel(const float* __restrict__ x,
                                                      float* __restrict__ out) {
    const int row    = blockIdx.y;
    const int chunk0 = blockIdx.x * CHUNK;
    const int tid    = threadIdx.x;

    // sA stages raw x first, then is overwritten (per-thread-own-segment,
    // with a barrier before any cross-thread read) by the a-cumsum.
    __shared__ __align__(16) float sA[NTOT];
    __shared__ __align__(16) float sB[NTOT];
    __shared__ float waveA[4];
    __shared__ float waveB[4];

    const float* xr = x + (size_t)row * L_DIM;

    // Phase 1: coalesced float4 staging of raw x (zero-fill outside the row)
    for (int g = tid; g < NG; g += T) {
        const int c = chunk0 - HALO + 4 * g;   // 4-aligned (HALO%4==0)
        fx4 v;
        if (c >= 0 && c + 3 < L_DIM) {
            v = *reinterpret_cast<const fx4*>(xr + c);
        } else {
            v.x = (c + 0 >= 0 && c + 0 < L_DIM) ? xr[c + 0] : 0.0f;
            v.y = (c + 1 >= 0 && c + 1 < L_DIM) ? xr[c + 1] : 0.0f;
            v.z = (c + 2 >= 0 && c + 2 < L_DIM) ? xr[c + 2] : 0.0f;
            v.w = (c + 3 >= 0 && c + 3 < L_DIM) ? xr[c + 3] : 0.0f;
        }
        *reinterpret_cast<fx4*>(&sA[4 * g]) = v;
    }
    __syncthreads();

    // Phase 2: per-thread transform + inclusive cumsum in registers.
    // log(max(1,1+x)) and log(max(1,1-x)) are never both nonzero:
    //   t = log(1+|x|);  a-term = (x>0) ? t : 0;  b-term = (x<0) ? t : 0.
    const int s0 = tid * EPT;
    const int s1 = min(NTOT, s0 + EPT);
    float ra[EPT], rb[EPT];
    float runA = 0.0f, runB = 0.0f;
    #pragma unroll
    for (int j = 0; j < EPT; ++j) {
        const int idx = s0 + j;
        const float v = (idx < s1) ? sA[idx] : 0.0f;
        const float t = __logf(1.0f + fabsf(v));
        runA += (v > 0.0f) ? t : 0.0f;
        runB += (v < 0.0f) ? t : 0.0f;
        ra[j] = runA; rb[j] = runB;
    }

    // Phase 3: block scan of segment totals (wave shuffle + wave totals)
    float vA = runA, vB = runB;
    const int lane = tid & 63;
    const int wid  = tid >> 6;
    #pragma unroll
    for (int d = 1; d < 64; d <<= 1) {
        float uA = __shfl_up(vA, d);
        float uB = __shfl_up(vB, d);
        if (lane >= d) { vA += uA; vB += uB; }
    }
    if (lane == 63) { waveA[wid] = vA; waveB[wid] = vB; }
    __syncthreads();
    float offA = vA - runA;   // exclusive prefix within wave
    float offB = vB - runB;
    #pragma unroll
    for (int w = 0; w < 3; ++w) {
        if (w < wid) { offA += waveA[w]; offB += waveB[w]; }
    }

    // Phase 4: single write pass of the final cumsum into LDS
    #pragma unroll
    for (int j = 0; j < EPT; ++j) {
        const int idx = s0 + j;
        if (idx < NTOT) { sA[idx] = ra[j] + offA; sB[idx] = rb[j] + offB; }
    }
    __syncthreads();

    // Phase 5: windows via aligned ds_read_b128 only (conflict-free pattern),
    // shifted windows assembled by register selects from adjacent float4s.
    //   cs[i]     -> L0[u]                  (L0 = cs[i0+0..3])
    //   cs[i+98]  -> {L1.z,L1.w,L2.x,L2.y}  (L1 = cs[i0+96..99], L2 = cs[i0+100..103])
    //   cs[i+101] -> {L2.y,L2.z,L2.w,L3.x}  (L3 = cs[i0+104..107])
    //   cs[i+199] -> {L4.w,L5.x,L5.y,L5.z}  (L4 = cs[i0+196..199], L5 = cs[i0+200..203])
    const float inv3   = 1.0f / 3.0f;
    const float inv199 = 1.0f / 199.0f;
    float* ob = out + (size_t)row * 4u * L_DIM + chunk0;
    #pragma unroll
    for (int it = 0; it < CHUNK / (4 * T); ++it) {   // 2 iterations
        const int i0 = 4 * (tid + it * T);
        fx4 r0, r1, r2, r3;
        #pragma unroll
        for (int arr = 0; arr < 2; ++arr) {
            const float* s = arr ? sB : sA;
            const fx4 L0 = *reinterpret_cast<const fx4*>(s + i0);
            const fx4 L1 = *reinterpret_cast<const fx4*>(s + i0 + 96);
            const fx4 L2 = *reinterpret_cast<const fx4*>(s + i0 + 100);
            const fx4 L3 = *reinterpret_cast<const fx4*>(s + i0 + 104);
            const fx4 L4 = *reinterpret_cast<const fx4*>(s + i0 + 196);
            const fx4 L5 = *reinterpret_cast<const fx4*>(s + i0 + 200);
            const float csI[4]   = {L0.x, L0.y, L0.z, L0.w};
            const float cs98[4]  = {L1.z, L1.w, L2.x, L2.y};
            const float cs101[4] = {L2.y, L2.z, L2.w, L3.x};
            const float cs199[4] = {L4.w, L5.x, L5.y, L5.z};
            fx4& rs = arr ? r3 : r1;   // plain k=3 pool
            fx4& rd = arr ? r2 : r0;   // k=3 - k=199
            #pragma unroll
            for (int u = 0; u < 4; ++u) {
                const float p0 = (cs101[u] - cs98[u]) * inv3;
                const float p5 = (cs199[u] - csI[u]) * inv199;
                rs[u] = p0;
                rd[u] = p0 - p5;
            }
        }
        *reinterpret_cast<fx4*>(ob + 0 * (size_t)L_DIM + i0) = r0;
        *reinterpret_cast<fx4*>(ob + 1 * (size_t)L_DIM + i0) = r1;
        *reinterpret_cast<fx4*>(ob + 2 * (size_t)L_DIM + i0) = r2;
        *reinterpret_cast<fx4*>(ob + 3 * (size_t)L_DIM + i0) = r3;
    }
}

extern "C" void kernel_launch(void* const* d_in, const int* in_sizes, int n_in,
                              void* d_out, int out_size, void* d_ws, size_t ws_size,
                              hipStream_t stream) {
    const float* x = (const float*)d_in[0];
    float* out = (float*)d_out;
    dim3 grid(L_DIM / CHUNK, B_DIM);
    pool_feat_kernel<<<grid, dim3(T), 0, stream>>>(x, out);
}

// Round 13
// 31.100 us; speedup vs baseline: 1.9185x; 1.0484x over previous
//
#include <hip/hip_runtime.h>

#define B_DIM 256
#define L_DIM 32768
#define CHUNK 2048
#define HALO  100
#define NTOT  (CHUNK + 2*HALO)   // 2248
#define NG    (NTOT/4)           // 562 float4 groups
#define T     256
#define EPT   9                  // ceil(NTOT / T)
#define NCH   2                  // chunks per block (software-pipelined)
#define NR    3                  // load rounds per chunk: ceil(NG/T)

typedef float fx4 __attribute__((ext_vector_type(4)));

__device__ __forceinline__ void issue_loads(const float* __restrict__ xr, int chunk0,
                                            int tid, fx4 p[NR]) {
    #pragma unroll
    for (int r = 0; r < NR; ++r) {
        const int g = tid + r * T;
        if (g < NG) {
            const int c = chunk0 - HALO + 4 * g;   // 4-aligned (HALO%4==0)
            if (c >= 0 && c + 3 < L_DIM) {
                p[r] = *reinterpret_cast<const fx4*>(xr + c);
            } else {
                p[r].x = (c + 0 >= 0 && c + 0 < L_DIM) ? xr[c + 0] : 0.0f;
                p[r].y = (c + 1 >= 0 && c + 1 < L_DIM) ? xr[c + 1] : 0.0f;
                p[r].z = (c + 2 >= 0 && c + 2 < L_DIM) ? xr[c + 2] : 0.0f;
                p[r].w = (c + 3 >= 0 && c + 3 < L_DIM) ? xr[c + 3] : 0.0f;
            }
        }
    }
}

__global__ __launch_bounds__(T) void pool_feat_kernel(const float* __restrict__ x,
                                                      float* __restrict__ out) {
    const int row  = blockIdx.y;
    const int base = blockIdx.x * (CHUNK * NCH);
    const int tid  = threadIdx.x;

    // sA holds, in sequence: raw x -> signed-log u -> a-cumsum. All in-place
    // overwrites are own-thread-segment with barriers before cross-thread reads.
    __shared__ __align__(16) float sA[NTOT];
    __shared__ __align__(16) float sB[NTOT];
    __shared__ float waveA[4];
    __shared__ float waveB[4];

    const float* xr = x + (size_t)row * L_DIM;

    fx4 pc[NR], pn[NR];
    issue_loads(xr, base, tid, pc);            // chunk 0 raw -> regs

    for (int k = 0; k < NCH; ++k) {
        const int chunk0 = base + k * CHUNK;

        // Stage current chunk's raw data into LDS
        #pragma unroll
        for (int r = 0; r < NR; ++r) {
            const int g = tid + r * T;
            if (g < NG) *reinterpret_cast<fx4*>(&sA[4 * g]) = pc[r];
        }
        // Prefetch next chunk: loads stay in flight through this chunk's
        // compute + store phases (consumed only at next iteration's staging).
        if (k + 1 < NCH) issue_loads(xr, chunk0 + CHUNK, tid, pn);
        __syncthreads();

        // Pass 1: transform in place + segment totals.
        // u = copysign(log(1+|x|), x); a-term = max(u,0), b-term = max(-u,0)
        // (log(max(1,1+x)) and log(max(1,1-x)) are never both nonzero).
        const int s0 = tid * EPT;
        const int s1 = min(NTOT, s0 + EPT);
        float runA = 0.0f, runB = 0.0f;
        for (int j = s0; j < s1; ++j) {
            const float v = sA[j];
            const float t = __logf(1.0f + fabsf(v));
            const float u = copysignf(t, v);
            runA += fmaxf(u, 0.0f);
            runB += fmaxf(-u, 0.0f);
            sA[j] = u;                         // raw consumed, store signed log
        }

        // Block scan of segment totals (wave shuffle + wave totals)
        float vA = runA, vB = runB;
        const int lane = tid & 63;
        const int wid  = tid >> 6;
        #pragma unroll
        for (int d = 1; d < 64; d <<= 1) {
            float uA = __shfl_up(vA, d);
            float uB = __shfl_up(vB, d);
            if (lane >= d) { vA += uA; vB += uB; }
        }
        if (lane == 63) { waveA[wid] = vA; waveB[wid] = vB; }
        __syncthreads();
        float offA = vA - runA;                // exclusive prefix within wave
        float offB = vB - runB;
        #pragma unroll
        for (int w = 0; w < 3; ++w) {
            if (w < wid) { offA += waveA[w]; offB += waveB[w]; }
        }

        // Pass 2: rebuild terms from u (no log recompute), write final cumsums
        float accA = offA, accB = offB;
        for (int j = s0; j < s1; ++j) {
            const float u = sA[j];
            accA += fmaxf(u, 0.0f);
            accB += fmaxf(-u, 0.0f);
            sA[j] = accA;
            sB[j] = accB;
        }
        __syncthreads();

        // Phase 5: windows via aligned ds_read_b128 only; shifted windows
        // assembled by register selects from adjacent float4s.
        const float inv3   = 1.0f / 3.0f;
        const float inv199 = 1.0f / 199.0f;
        float* ob = out + (size_t)row * 4u * L_DIM + chunk0;
        #pragma unroll
        for (int it = 0; it < CHUNK / (4 * T); ++it) {   // 2 iterations
            const int i0 = 4 * (tid + it * T);
            fx4 r0, r1, r2, r3;
            #pragma unroll
            for (int arr = 0; arr < 2; ++arr) {
                const float* s = arr ? sB : sA;
                const fx4 L0 = *reinterpret_cast<const fx4*>(s + i0);
                const fx4 L1 = *reinterpret_cast<const fx4*>(s + i0 + 96);
                const fx4 L2 = *reinterpret_cast<const fx4*>(s + i0 + 100);
                const fx4 L3 = *reinterpret_cast<const fx4*>(s + i0 + 104);
                const fx4 L4 = *reinterpret_cast<const fx4*>(s + i0 + 196);
                const fx4 L5 = *reinterpret_cast<const fx4*>(s + i0 + 200);
                const float csI[4]   = {L0.x, L0.y, L0.z, L0.w};
                const float cs98[4]  = {L1.z, L1.w, L2.x, L2.y};
                const float cs101[4] = {L2.y, L2.z, L2.w, L3.x};
                const float cs199[4] = {L4.w, L5.x, L5.y, L5.z};
                fx4& rs = arr ? r3 : r1;   // plain k=3 pool
                fx4& rd = arr ? r2 : r0;   // k=3 - k=199
                #pragma unroll
                for (int u = 0; u < 4; ++u) {
                    const float p0 = (cs101[u] - cs98[u]) * inv3;
                    const float p5 = (cs199[u] - csI[u]) * inv199;
                    rs[u] = p0;
                    rd[u] = p0 - p5;
                }
            }
            *reinterpret_cast<fx4*>(ob + 0 * (size_t)L_DIM + i0) = r0;
            *reinterpret_cast<fx4*>(ob + 1 * (size_t)L_DIM + i0) = r1;
            *reinterpret_cast<fx4*>(ob + 2 * (size_t)L_DIM + i0) = r2;
            *reinterpret_cast<fx4*>(ob + 3 * (size_t)L_DIM + i0) = r3;
        }

        if (k + 1 < NCH) {
            __syncthreads();                   // sA reads done before restaging
            #pragma unroll
            for (int r = 0; r < NR; ++r) pc[r] = pn[r];
        }
    }
}

extern "C" void kernel_launch(void* const* d_in, const int* in_sizes, int n_in,
                              void* d_out, int out_size, void* d_ws, size_t ws_size,
                              hipStream_t stream) {
    const float* x = (const float*)d_in[0];
    float* out = (float*)d_out;
    dim3 grid(L_DIM / (CHUNK * NCH), B_DIM);
    pool_feat_kernel<<<grid, dim3(T), 0, stream>>>(x, out);
}